// Round 8
// baseline (94.343 us; speedup 1.0000x reference)
//
#include <hip/hip_runtime.h>
#include <hip/hip_bf16.h>

typedef __attribute__((ext_vector_type(8))) short short8;
typedef __attribute__((ext_vector_type(4))) float f32x4;

#define LDSW 136  // padded row stride (bf16 elems) = 272 B

// round-to-nearest-even f32 -> bf16
static __device__ __forceinline__ ushort f2bf(float f) {
  unsigned int u = __builtin_bit_cast(unsigned int, f);
  u += 0x7fffu + ((u >> 16) & 1u);
  return (ushort)(u >> 16);
}

// ---------------- kernel 1: pack w1 (f32 row-major) -> bf16 [col][k] with padded stride ----
__global__ __launch_bounds__(256) void pack_w1_kernel(const float* __restrict__ w1,
                                                      ushort* __restrict__ w1p) {
  int tid = blockIdx.x * 256 + threadIdx.x;
  int k = tid >> 7;
  int c = tid & 127;
  w1p[c * LDSW + k] = f2bf(w1[k * 128 + c]);
}

// ---------------- kernel 2: FUSED gemm + colsum ---------------------------------------------
// Six standalone colsum variants all read x at ~1.7 TB/s; this gemm structure reads the same
// x (+ writes out) in ~15us. So the colsum is computed HERE, from the already-loaded f32
// fragments, before bf16 conversion: each block's threads touch each x element of its 64-row
// tile exactly once (thread = row rbase+c, cols kb*32+kg*8..+7). Cross-row (c-lane) reduce is
// a 4-step shfl_xor butterfly within each 16-lane group; leaders stash to 2KB LDS; a final
// 128-thread pass emits the block's colsum partial. lin (= x@w1) goes to d_out; t is added by
// add_t_kernel afterwards (t isn't known until all partials exist).
__global__ __launch_bounds__(256) void gemm_cs_kernel(const float* __restrict__ x,
                                                      const ushort* __restrict__ w1p,
                                                      float* __restrict__ out,
                                                      float* __restrict__ partial) {
  __shared__ ushort w1t[128 * LDSW];   // 34816 B
  __shared__ float cs_lds[4][128];     // 2048 B: per-wave colsum partials
  int tid = threadIdx.x;

  {
    const ulonglong2* src = reinterpret_cast<const ulonglong2*>(w1p);
    ulonglong2* dst = reinterpret_cast<ulonglong2*>(w1t);
#pragma unroll
    for (int i = 0; i < (128 * LDSW * 2) / 16 / 256 + 1; ++i) {
      int idx = tid + i * 256;
      if (idx < (128 * LDSW * 2) / 16) dst[idx] = src[idx];
    }
  }
  __syncthreads();

  int lane = tid & 63;
  int wave = tid >> 6;
  int c = lane & 15;    // A row-in-tile / B col / D col
  int kg = lane >> 4;   // k-group 0..3
  int rbase = blockIdx.x * 64 + wave * 16;
  const float* xrow = x + (size_t)(rbase + c) * 128;

  f32x4 acc[8];
#pragma unroll
  for (int nb = 0; nb < 8; ++nb) acc[nb] = (f32x4){0.f, 0.f, 0.f, 0.f};

#pragma unroll
  for (int kb = 0; kb < 4; ++kb) {
    int k0 = kb * 32 + kg * 8;
    float4 a0 = *reinterpret_cast<const float4*>(xrow + k0);
    float4 a1 = *reinterpret_cast<const float4*>(xrow + k0 + 4);

    // colsum: butterfly-sum across the 16 rows held by this 16-lane group (f32, pre-convert)
    float cs[8] = {a0.x, a0.y, a0.z, a0.w, a1.x, a1.y, a1.z, a1.w};
#pragma unroll
    for (int m = 8; m >= 1; m >>= 1) {
#pragma unroll
      for (int v = 0; v < 8; ++v) cs[v] += __shfl_xor(cs[v], m, 16);
    }
    if (c == 0) {
      float4 lo = {cs[0], cs[1], cs[2], cs[3]};
      float4 hi = {cs[4], cs[5], cs[6], cs[7]};
      *reinterpret_cast<float4*>(&cs_lds[wave][k0]) = lo;
      *reinterpret_cast<float4*>(&cs_lds[wave][k0 + 4]) = hi;
    }

    short8 afrag;
    afrag[0] = (short)f2bf(a0.x);
    afrag[1] = (short)f2bf(a0.y);
    afrag[2] = (short)f2bf(a0.z);
    afrag[3] = (short)f2bf(a0.w);
    afrag[4] = (short)f2bf(a1.x);
    afrag[5] = (short)f2bf(a1.y);
    afrag[6] = (short)f2bf(a1.z);
    afrag[7] = (short)f2bf(a1.w);
#pragma unroll
    for (int nb = 0; nb < 8; ++nb) {
      short8 bfrag = *reinterpret_cast<const short8*>(&w1t[(nb * 16 + c) * LDSW + k0]);
      acc[nb] = __builtin_amdgcn_mfma_f32_16x16x32_bf16(afrag, bfrag, acc[nb], 0, 0, 0);
    }
  }

  // write lin (D layout m89-verified: col = lane&15, row = (lane>>4)*4 + reg)
#pragma unroll
  for (int nb = 0; nb < 8; ++nb) {
    int col = nb * 16 + c;
#pragma unroll
    for (int i = 0; i < 4; ++i) {
      out[(size_t)(rbase + kg * 4 + i) * 128 + col] = acc[nb][i];
    }
  }

  // block colsum partial = sum of the 4 per-wave partials
  __syncthreads();
  if (tid < 128) {
    float s = cs_lds[0][tid] + cs_lds[1][tid] + cs_lds[2][tid] + cs_lds[3][tid];
    partial[(size_t)blockIdx.x * 128 + tid] = s;
  }
}

// ---------------- kernel 3: reduce partial[3125][128] -> partial2[128][128] ----------------
__global__ __launch_bounds__(256) void reduce_kernel(const float* __restrict__ partial,
                                                     float* __restrict__ partial2,
                                                     int nb) {
  int tid = threadIdx.x;
  int j = tid & 127;
  int orow = blockIdx.x * 2 + (tid >> 7);  // 64 blocks -> orow 0..127
  float s = 0.f;
  for (int r = orow; r < nb; r += 128) s += partial[(size_t)r * 128 + j];
  partial2[orow * 128 + j] = s;
}

// ---------------- kernel 4: t = (pooled @ w2)/n + bias  (1 block x 1024 thr) ---------------
__global__ __launch_bounds__(1024) void transmit_kernel(const float* __restrict__ partial,
                                                        const float* __restrict__ w2,
                                                        const float* __restrict__ bias,
                                                        float* __restrict__ t, int n,
                                                        int nblocks) {
  __shared__ float red[8][128];
  __shared__ float pooled[128];
  int tid = threadIdx.x;
  int j = tid & 127;
  int g = tid >> 7;

  float s = 0.f;
  for (int b = g; b < nblocks; b += 8) s += partial[b * 128 + j];
  red[g][j] = s;
  __syncthreads();
  if (tid < 128) {
    float p = 0.f;
#pragma unroll
    for (int gg = 0; gg < 8; ++gg) p += red[gg][j];
    pooled[j] = p;
  }
  __syncthreads();

  float acc = 0.f;
#pragma unroll
  for (int ii = 0; ii < 16; ++ii) {
    int i = g * 16 + ii;
    acc += pooled[i] * w2[i * 128 + j];
  }
  __syncthreads();
  red[g][j] = acc;
  __syncthreads();
  if (tid < 128) {
    float a = 0.f;
#pragma unroll
    for (int gg = 0; gg < 8; ++gg) a += red[gg][j];
    t[j] = a / (float)n + bias[j];
  }
}

// ---------------- kernel 5: out += t (broadcast over columns) ------------------------------
// Copy-shaped RMW over out, which is L3-dirty-resident (gemm_cs just wrote it; working set
// x+out = 205MB < 256MB L3). Grid stride 524288 % 32 == 0 -> each thread's t-phase constant.
__global__ __launch_bounds__(256) void add_t_kernel(float4* __restrict__ out4,
                                                    const float4* __restrict__ t4,
                                                    int total4) {
  int idx = blockIdx.x * 256 + threadIdx.x;     // 2048*256 = 524288 threads
  float4 tv = t4[idx & 31];
  const int STRIDE = 524288;
#pragma unroll
  for (int i = 0; i < 12; ++i) {
    size_t k = (size_t)idx + (size_t)i * STRIDE;
    float4 v = out4[k];
    v.x += tv.x; v.y += tv.y; v.z += tv.z; v.w += tv.w;
    out4[k] = v;
  }
  size_t k = (size_t)idx + (size_t)12 * STRIDE;  // tail: 108544 float4
  if (k < (size_t)total4) {
    float4 v = out4[k];
    v.x += tv.x; v.y += tv.y; v.z += tv.z; v.w += tv.w;
    out4[k] = v;
  }
}

extern "C" void kernel_launch(void* const* d_in, const int* in_sizes, int n_in,
                              void* d_out, int out_size, void* d_ws, size_t ws_size,
                              hipStream_t stream) {
  const float* x = (const float*)d_in[0];
  const float* w1 = (const float*)d_in[1];
  const float* w2 = (const float*)d_in[2];
  const float* bias = (const float*)d_in[3];
  float* out = (float*)d_out;
  int n = in_sizes[0] / 128;  // 200000
  int nb = n / 64;            // 3125 gemm blocks

  char* ws = (char*)d_ws;
  float* t = (float*)ws;                     // 512 B
  ushort* w1p = (ushort*)(ws + 512);         // 34,816 B -> ends 35,328
  float* partial = (float*)(ws + 35328);     // 3125*128*4 = 1,600,000 B -> ends 1,635,328
  float* partial2 = (float*)(ws + 1635328);  // 128*128*4 = 65,536 B

  hipLaunchKernelGGL(pack_w1_kernel, dim3(64), dim3(256), 0, stream, w1, w1p);
  hipLaunchKernelGGL(gemm_cs_kernel, dim3(nb), dim3(256), 0, stream, x, w1p, out, partial);
  hipLaunchKernelGGL(reduce_kernel, dim3(64), dim3(256), 0, stream, partial, partial2, nb);
  hipLaunchKernelGGL(transmit_kernel, dim3(1), dim3(1024), 0, stream,
                     partial2, w2, bias, t, n, 128);
  hipLaunchKernelGGL(add_t_kernel, dim3(2048), dim3(256), 0, stream,
                     (float4*)out, (const float4*)t, out_size / 4);
}

// Round 9
// 90.566 us; speedup vs baseline: 1.0417x; 1.0417x over previous
//
#include <hip/hip_runtime.h>
#include <hip/hip_bf16.h>

typedef __attribute__((ext_vector_type(8))) short short8;
typedef __attribute__((ext_vector_type(4))) float f32x4;

#define LDSW 136  // padded row stride (bf16 elems) = 272 B

// round-to-nearest-even f32 -> bf16
static __device__ __forceinline__ ushort f2bf(float f) {
  unsigned int u = __builtin_bit_cast(unsigned int, f);
  u += 0x7fffu + ((u >> 16) & 1u);
  return (ushort)(u >> 16);
}

// ---------------- kernel 1: pack w1 (f32 row-major) -> bf16 [col][k] with padded stride ----
__global__ __launch_bounds__(256) void pack_w1_kernel(const float* __restrict__ w1,
                                                      ushort* __restrict__ w1p) {
  int tid = blockIdx.x * 256 + threadIdx.x;
  int k = tid >> 7;
  int c = tid & 127;
  w1p[c * LDSW + k] = f2bf(w1[k * 128 + c]);
}

// ---------------- kernel 2: FUSED gemm + colsum, cross-lane work OUT of the hot loop -------
// R8 lesson (direct counters): injecting a shfl_xor butterfly per k-block made the kernel
// 63us even L3-warm (everything idle) — it turned each load's consumer into a dependent
// ds_bpermute chain and killed load hoisting. Fix: the thread's colsum contribution IS its
// 32 loaded f32 values (each x element is touched exactly once per block). So hold the 8
// loaded float4s in registers, run the main loop exactly like the proven-fast gemm
// (all loads hoisted -> f2bf -> MFMA), and do the cross-thread column reduce ONCE in the
// epilogue via LDS scratch (reusing w1t's 34.8KB after the last B-fragment read).
__global__ __launch_bounds__(256) void gemm_cs2_kernel(const float* __restrict__ x,
                                                       const ushort* __restrict__ w1p,
                                                       float* __restrict__ out,
                                                       float* __restrict__ partial) {
  __shared__ ushort w1t[128 * LDSW];  // 34816 B; reused as f32 scratch [4][64][33] (33792 B)
  int tid = threadIdx.x;

  {
    const ulonglong2* src = reinterpret_cast<const ulonglong2*>(w1p);
    ulonglong2* dst = reinterpret_cast<ulonglong2*>(w1t);
#pragma unroll
    for (int i = 0; i < (128 * LDSW * 2) / 16 / 256 + 1; ++i) {
      int idx = tid + i * 256;
      if (idx < (128 * LDSW * 2) / 16) dst[idx] = src[idx];
    }
  }
  __syncthreads();

  int lane = tid & 63;
  int wave = tid >> 6;
  int c = lane & 15;    // A row-in-tile / B col / D col
  int kg = lane >> 4;   // k-group 0..3
  int rbase = blockIdx.x * 64 + wave * 16;
  const float* xrow = x + (size_t)(rbase + c) * 128;

  // ---- load phase: all 8 independent dwordx4, hoisted, kept live for the colsum epilogue
  float4 A0[4], A1[4];
#pragma unroll
  for (int kb = 0; kb < 4; ++kb) {
    int k0 = kb * 32 + kg * 8;
    A0[kb] = *reinterpret_cast<const float4*>(xrow + k0);
    A1[kb] = *reinterpret_cast<const float4*>(xrow + k0 + 4);
  }

  // ---- MFMA phase (identical to the proven-fast gemm)
  f32x4 acc[8];
#pragma unroll
  for (int nb = 0; nb < 8; ++nb) acc[nb] = (f32x4){0.f, 0.f, 0.f, 0.f};
#pragma unroll
  for (int kb = 0; kb < 4; ++kb) {
    int k0 = kb * 32 + kg * 8;
    short8 afrag;
    afrag[0] = (short)f2bf(A0[kb].x);
    afrag[1] = (short)f2bf(A0[kb].y);
    afrag[2] = (short)f2bf(A0[kb].z);
    afrag[3] = (short)f2bf(A0[kb].w);
    afrag[4] = (short)f2bf(A1[kb].x);
    afrag[5] = (short)f2bf(A1[kb].y);
    afrag[6] = (short)f2bf(A1[kb].z);
    afrag[7] = (short)f2bf(A1[kb].w);
#pragma unroll
    for (int nb = 0; nb < 8; ++nb) {
      short8 bfrag = *reinterpret_cast<const short8*>(&w1t[(nb * 16 + c) * LDSW + k0]);
      acc[nb] = __builtin_amdgcn_mfma_f32_16x16x32_bf16(afrag, bfrag, acc[nb], 0, 0, 0);
    }
  }

  // ---- out = lin (D layout m89-verified: col = lane&15, row = (lane>>4)*4 + reg)
#pragma unroll
  for (int nb = 0; nb < 8; ++nb) {
    int col = nb * 16 + c;
#pragma unroll
    for (int i = 0; i < 4; ++i) {
      out[(size_t)(rbase + kg * 4 + i) * 128 + col] = acc[nb][i];
    }
  }

  // ---- colsum epilogue: one LDS pass, zero cross-lane ops in the main loop
  __syncthreads();  // all waves done reading w1t -> safe to reuse as scratch
  float* scratch = reinterpret_cast<float*>(w1t);  // [kg][row 0..63][idx 0..32] pad 33
  {
    int r = wave * 16 + c;
    int base = (kg * 64 + r) * 33;
#pragma unroll
    for (int kb = 0; kb < 4; ++kb) {
      scratch[base + kb * 8 + 0] = A0[kb].x;
      scratch[base + kb * 8 + 1] = A0[kb].y;
      scratch[base + kb * 8 + 2] = A0[kb].z;
      scratch[base + kb * 8 + 3] = A0[kb].w;
      scratch[base + kb * 8 + 4] = A1[kb].x;
      scratch[base + kb * 8 + 5] = A1[kb].y;
      scratch[base + kb * 8 + 6] = A1[kb].z;
      scratch[base + kb * 8 + 7] = A1[kb].w;
    }
  }
  __syncthreads();
  if (tid < 128) {
    int col = tid;
    int kgg = (col >> 3) & 3;             // which k-group held this col
    int idx = (col >> 5) * 8 + (col & 7); // kb*8 + j
    float s = 0.f;
#pragma unroll 8
    for (int r = 0; r < 64; ++r) s += scratch[(kgg * 64 + r) * 33 + idx];
    partial[(size_t)blockIdx.x * 128 + col] = s;
  }
}

// ---------------- kernel 3: reduce partial[3125][128] -> partial2[128][128] ----------------
__global__ __launch_bounds__(256) void reduce_kernel(const float* __restrict__ partial,
                                                     float* __restrict__ partial2,
                                                     int nb) {
  int tid = threadIdx.x;
  int j = tid & 127;
  int orow = blockIdx.x * 2 + (tid >> 7);  // 64 blocks -> orow 0..127
  float s = 0.f;
  for (int r = orow; r < nb; r += 128) s += partial[(size_t)r * 128 + j];
  partial2[orow * 128 + j] = s;
}

// ---------------- kernel 4: t = (pooled @ w2)/n + bias  (1 block x 1024 thr) ---------------
__global__ __launch_bounds__(1024) void transmit_kernel(const float* __restrict__ partial,
                                                        const float* __restrict__ w2,
                                                        const float* __restrict__ bias,
                                                        float* __restrict__ t, int n,
                                                        int nblocks) {
  __shared__ float red[8][128];
  __shared__ float pooled[128];
  int tid = threadIdx.x;
  int j = tid & 127;
  int g = tid >> 7;

  float s = 0.f;
  for (int b = g; b < nblocks; b += 8) s += partial[b * 128 + j];
  red[g][j] = s;
  __syncthreads();
  if (tid < 128) {
    float p = 0.f;
#pragma unroll
    for (int gg = 0; gg < 8; ++gg) p += red[gg][j];
    pooled[j] = p;
  }
  __syncthreads();

  float acc = 0.f;
#pragma unroll
  for (int ii = 0; ii < 16; ++ii) {
    int i = g * 16 + ii;
    acc += pooled[i] * w2[i * 128 + j];
  }
  __syncthreads();
  red[g][j] = acc;
  __syncthreads();
  if (tid < 128) {
    float a = 0.f;
#pragma unroll
    for (int gg = 0; gg < 8; ++gg) a += red[gg][j];
    t[j] = a / (float)n + bias[j];
  }
}

// ---------------- kernel 5: out += t  (exact tiling, batched 4-deep RMW) -------------------
// 3125 blocks x 256 thr x 8 float4 = 6,400,000 exact. Stride 800000 % 32 == 0 -> constant
// t-phase per thread. out is L3-dirty-resident (gemm_cs2 just wrote it; x+out = 205MB < 256).
__global__ __launch_bounds__(256) void add_t_kernel(float4* __restrict__ out4,
                                                    const float4* __restrict__ t4) {
  int idx = blockIdx.x * 256 + threadIdx.x;  // 0..799999
  float4 tv = t4[idx & 31];
#pragma unroll
  for (int b = 0; b < 2; ++b) {
    float4 v0 = out4[(size_t)idx + (size_t)(b * 4 + 0) * 800000u];
    float4 v1 = out4[(size_t)idx + (size_t)(b * 4 + 1) * 800000u];
    float4 v2 = out4[(size_t)idx + (size_t)(b * 4 + 2) * 800000u];
    float4 v3 = out4[(size_t)idx + (size_t)(b * 4 + 3) * 800000u];
    v0.x += tv.x; v0.y += tv.y; v0.z += tv.z; v0.w += tv.w;
    v1.x += tv.x; v1.y += tv.y; v1.z += tv.z; v1.w += tv.w;
    v2.x += tv.x; v2.y += tv.y; v2.z += tv.z; v2.w += tv.w;
    v3.x += tv.x; v3.y += tv.y; v3.z += tv.z; v3.w += tv.w;
    out4[(size_t)idx + (size_t)(b * 4 + 0) * 800000u] = v0;
    out4[(size_t)idx + (size_t)(b * 4 + 1) * 800000u] = v1;
    out4[(size_t)idx + (size_t)(b * 4 + 2) * 800000u] = v2;
    out4[(size_t)idx + (size_t)(b * 4 + 3) * 800000u] = v3;
  }
}

extern "C" void kernel_launch(void* const* d_in, const int* in_sizes, int n_in,
                              void* d_out, int out_size, void* d_ws, size_t ws_size,
                              hipStream_t stream) {
  const float* x = (const float*)d_in[0];
  const float* w1 = (const float*)d_in[1];
  const float* w2 = (const float*)d_in[2];
  const float* bias = (const float*)d_in[3];
  float* out = (float*)d_out;
  int n = in_sizes[0] / 128;  // 200000
  int nb = n / 64;            // 3125 gemm blocks

  char* ws = (char*)d_ws;
  float* t = (float*)ws;                     // 512 B
  ushort* w1p = (ushort*)(ws + 512);         // 34,816 B -> ends 35,328
  float* partial = (float*)(ws + 35328);     // 3125*128*4 = 1,600,000 B -> ends 1,635,328
  float* partial2 = (float*)(ws + 1635328);  // 128*128*4 = 65,536 B

  hipLaunchKernelGGL(pack_w1_kernel, dim3(64), dim3(256), 0, stream, w1, w1p);
  hipLaunchKernelGGL(gemm_cs2_kernel, dim3(nb), dim3(256), 0, stream, x, w1p, out, partial);
  hipLaunchKernelGGL(reduce_kernel, dim3(64), dim3(256), 0, stream, partial, partial2, nb);
  hipLaunchKernelGGL(transmit_kernel, dim3(1), dim3(1024), 0, stream,
                     partial2, w2, bias, t, n, 128);
  hipLaunchKernelGGL(add_t_kernel, dim3(nb), dim3(256), 0, stream,
                     (float4*)out, (const float4*)t);
}

// Round 10
// 74.912 us; speedup vs baseline: 1.2594x; 1.2090x over previous
//
#include <hip/hip_runtime.h>
#include <hip/hip_bf16.h>

typedef __attribute__((ext_vector_type(8))) short short8;
typedef __attribute__((ext_vector_type(4))) float f32x4;
typedef unsigned int u32;

#define LDSW 136  // padded row stride (bf16 elems) = 272 B

// round-to-nearest-even f32 -> bf16
static __device__ __forceinline__ ushort f2bf(float f) {
  unsigned int u = __builtin_bit_cast(unsigned int, f);
  u += 0x7fffu + ((u >> 16) & 1u);
  return (ushort)(u >> 16);
}

// ---------------- kernel 1: pack w1 (f32 row-major) -> bf16 [col][k] with padded stride ----
__global__ __launch_bounds__(256) void pack_w1_kernel(const float* __restrict__ w1,
                                                      ushort* __restrict__ w1p) {
  int tid = blockIdx.x * 256 + threadIdx.x;
  int k = tid >> 7;
  int c = tid & 127;
  w1p[c * LDSW + k] = f2bf(w1[k * 128 + c]);
}

// ---------------- kernel 2: column-sum via global_load_lds (DMA-to-LDS read path) ----------
// Ledger R2-R9: every VGPR-destination read of x from HBM caps at ~1.7-2.5 TB/s effective,
// invariant to occupancy/ILP/pattern/store-pairing. This kernel probes the ONE untried read
// mechanism: global_load_lds (direct HBM->LDS DMA, no VGPR round-trip; the m97 GEMM's +67%
// staging lever). Each block stages its 64-row tile (32KB, 3125*32768B = 102,400,000 exact)
// with 8 x 16B-wide gload_lds per wave, one barrier (drains vmcnt), then reduces from LDS.
// ~4 blocks/CU co-resident overlap stage & consume across blocks.
__global__ __launch_bounds__(256) void colsum_lds_kernel(const float* __restrict__ x,
                                                         float4* __restrict__ partial4) {
  __shared__ float tile[8192];     // 32 KB: 64 rows x 128 cols
  __shared__ float4 red[8][32];    // 4 KB
  int tid = threadIdx.x;
  int lane = tid & 63;
  int wave = tid >> 6;

  // stage: wave w, call i -> LDS floats [(w*8+i)*256 .. +256), global same offset + lane*4
  const float* gbase = x + (size_t)blockIdx.x * 8192 + (size_t)(wave * 8) * 256 + lane * 4;
  float* lbase = tile + (wave * 8) * 256;  // wave-uniform
#pragma unroll
  for (int i = 0; i < 8; ++i) {
    __builtin_amdgcn_global_load_lds(
        (const __attribute__((address_space(1))) u32*)(gbase + i * 256),
        (__attribute__((address_space(3))) u32*)(lbase + i * 256), 16, 0, 0);
  }
  __syncthreads();  // vmcnt(0) drain + barrier: tile complete

  // consume: thread t -> float4-col c4 = t&31, row group rg = t>>5 (rows rg, rg+8, ..., rg+56)
  int c4 = tid & 31;
  int rg = tid >> 5;
  const float4* tile4 = reinterpret_cast<const float4*>(tile);
  float4 acc = {0.f, 0.f, 0.f, 0.f};
#pragma unroll
  for (int k = 0; k < 8; ++k) {
    float4 v = tile4[(rg + 8 * k) * 32 + c4];  // wave reads contiguous 1KB: conflict-free
    acc.x += v.x; acc.y += v.y; acc.z += v.z; acc.w += v.w;
  }
  red[rg][c4] = acc;
  __syncthreads();
  if (tid < 32) {
    float4 s = red[0][tid];
#pragma unroll
    for (int g = 1; g < 8; ++g) {
      float4 v = red[g][tid];
      s.x += v.x; s.y += v.y; s.z += v.z; s.w += v.w;
    }
    partial4[(size_t)blockIdx.x * 32 + tid] = s;
  }
}

// ---------------- kernel 3: reduce partial[3125][128] -> partial2[128][128] ----------------
__global__ __launch_bounds__(256) void reduce_kernel(const float* __restrict__ partial,
                                                     float* __restrict__ partial2,
                                                     int nb) {
  int tid = threadIdx.x;
  int j = tid & 127;
  int orow = blockIdx.x * 2 + (tid >> 7);  // 64 blocks -> orow 0..127
  float s = 0.f;
  for (int r = orow; r < nb; r += 128) s += partial[(size_t)r * 128 + j];
  partial2[orow * 128 + j] = s;
}

// ---------------- kernel 4: t = (pooled @ w2)/n + bias  (1 block x 1024 thr) ---------------
__global__ __launch_bounds__(1024) void transmit_kernel(const float* __restrict__ partial,
                                                        const float* __restrict__ w2,
                                                        const float* __restrict__ bias,
                                                        float* __restrict__ t, int n,
                                                        int nblocks) {
  __shared__ float red[8][128];
  __shared__ float pooled[128];
  int tid = threadIdx.x;
  int j = tid & 127;
  int g = tid >> 7;

  float s = 0.f;
  for (int b = g; b < nblocks; b += 8) s += partial[b * 128 + j];
  red[g][j] = s;
  __syncthreads();
  if (tid < 128) {
    float p = 0.f;
#pragma unroll
    for (int gg = 0; gg < 8; ++gg) p += red[gg][j];
    pooled[j] = p;
  }
  __syncthreads();

  float acc = 0.f;
#pragma unroll
  for (int ii = 0; ii < 16; ++ii) {
    int i = g * 16 + ii;
    acc += pooled[i] * w2[i * 128 + j];
  }
  __syncthreads();
  red[g][j] = acc;
  __syncthreads();
  if (tid < 128) {
    float a = 0.f;
#pragma unroll
    for (int gg = 0; gg < 8; ++gg) a += red[gg][j];
    t[j] = a / (float)n + bias[j];
  }
}

// ---------------- kernel 5: out = x @ w1 + t  (bf16 MFMA; x L3-warm from colsum) -----------
__global__ __launch_bounds__(256) void gemm_kernel(const float* __restrict__ x,
                                                   const ushort* __restrict__ w1p,
                                                   const float* __restrict__ tvec,
                                                   float* __restrict__ out) {
  __shared__ ushort w1t[128 * LDSW];
  __shared__ float t_lds[128];
  int tid = threadIdx.x;

  {
    const ulonglong2* src = reinterpret_cast<const ulonglong2*>(w1p);
    ulonglong2* dst = reinterpret_cast<ulonglong2*>(w1t);
#pragma unroll
    for (int i = 0; i < (128 * LDSW * 2) / 16 / 256 + 1; ++i) {
      int idx = tid + i * 256;
      if (idx < (128 * LDSW * 2) / 16) dst[idx] = src[idx];
    }
  }
  if (tid < 128) t_lds[tid] = tvec[tid];
  __syncthreads();

  int lane = tid & 63;
  int wave = tid >> 6;
  int c = lane & 15;    // A row-in-tile / B col / D col
  int kg = lane >> 4;   // k-group 0..3
  int rbase = blockIdx.x * 64 + wave * 16;
  const float* xrow = x + (size_t)(rbase + c) * 128;

  f32x4 acc[8];
#pragma unroll
  for (int nb = 0; nb < 8; ++nb) acc[nb] = (f32x4){0.f, 0.f, 0.f, 0.f};

#pragma unroll
  for (int kb = 0; kb < 4; ++kb) {
    int k0 = kb * 32 + kg * 8;
    float4 a0 = *reinterpret_cast<const float4*>(xrow + k0);
    float4 a1 = *reinterpret_cast<const float4*>(xrow + k0 + 4);
    short8 afrag;
    afrag[0] = (short)f2bf(a0.x);
    afrag[1] = (short)f2bf(a0.y);
    afrag[2] = (short)f2bf(a0.z);
    afrag[3] = (short)f2bf(a0.w);
    afrag[4] = (short)f2bf(a1.x);
    afrag[5] = (short)f2bf(a1.y);
    afrag[6] = (short)f2bf(a1.z);
    afrag[7] = (short)f2bf(a1.w);
#pragma unroll
    for (int nb = 0; nb < 8; ++nb) {
      short8 bfrag = *reinterpret_cast<const short8*>(&w1t[(nb * 16 + c) * LDSW + k0]);
      acc[nb] = __builtin_amdgcn_mfma_f32_16x16x32_bf16(afrag, bfrag, acc[nb], 0, 0, 0);
    }
  }

  // D layout (m89-verified): col = lane&15, row = (lane>>4)*4 + reg
#pragma unroll
  for (int nb = 0; nb < 8; ++nb) {
    int col = nb * 16 + c;
    float tv = t_lds[col];
#pragma unroll
    for (int i = 0; i < 4; ++i) {
      out[(size_t)(rbase + kg * 4 + i) * 128 + col] = acc[nb][i] + tv;
    }
  }
}

extern "C" void kernel_launch(void* const* d_in, const int* in_sizes, int n_in,
                              void* d_out, int out_size, void* d_ws, size_t ws_size,
                              hipStream_t stream) {
  const float* x = (const float*)d_in[0];
  const float* w1 = (const float*)d_in[1];
  const float* w2 = (const float*)d_in[2];
  const float* bias = (const float*)d_in[3];
  float* out = (float*)d_out;
  int n = in_sizes[0] / 128;  // 200000
  int nb = n / 64;            // 3125 tile blocks

  char* ws = (char*)d_ws;
  float* t = (float*)ws;                     // 512 B
  ushort* w1p = (ushort*)(ws + 512);         // 34,816 B -> ends 35,328
  float* partial = (float*)(ws + 35328);     // 3125*128*4 = 1,600,000 B -> ends 1,635,328
  float* partial2 = (float*)(ws + 1635328);  // 128*128*4 = 65,536 B

  hipLaunchKernelGGL(pack_w1_kernel, dim3(64), dim3(256), 0, stream, w1, w1p);
  hipLaunchKernelGGL(colsum_lds_kernel, dim3(nb), dim3(256), 0, stream,
                     x, (float4*)partial);
  hipLaunchKernelGGL(reduce_kernel, dim3(64), dim3(256), 0, stream, partial, partial2, nb);
  hipLaunchKernelGGL(transmit_kernel, dim3(1), dim3(1024), 0, stream,
                     partial2, w2, bias, t, n, 128);
  hipLaunchKernelGGL(gemm_kernel, dim3(nb), dim3(256), 0, stream, x, w1p, t, out);
}